// Round 3
// baseline (777.880 us; speedup 1.0000x reference)
//
#include <hip/hip_runtime.h>
#include <hip/hip_bf16.h>

typedef __attribute__((ext_vector_type(8))) short short8;
typedef __attribute__((ext_vector_type(4))) float floatx4;
typedef unsigned short u16;
typedef unsigned int u32;

#define D 128          // IN == OUT == 128
#define CHUNK 256      // rows per block
#define NG 16          // 16-row groups per chunk

static __device__ __forceinline__ u16 f2bf(float f) {
  union { float f; u32 u; } v; v.f = f;
  u32 r = v.u + 0x7fffu + ((v.u >> 16) & 1u);   // RNE round to bf16
  return (u16)(r >> 16);
}

// pack two f32 -> two bf16 (round-half-up: differs from RNE only on exact ties)
// result = (bf(hi) << 16) | bf(lo)
static __device__ __forceinline__ u32 pk2bf(float lo, float hi) {
  union { float f; u32 u; } a, b;
  a.f = lo; b.f = hi;
  return __builtin_amdgcn_perm(b.u + 0x8000u, a.u + 0x8000u, 0x07060302);
}

// ---------------- prep: zero S, build W1^T in bf16 ----------------
__global__ void prep_kernel(const float* __restrict__ W1, u16* __restrict__ W1T,
                            float* __restrict__ S, int nS)
{
  int t = blockIdx.x * blockDim.x + threadIdx.x;
  if (t < D * D) {
    int k = t >> 7;          // W1 row (input dim)
    int n = t & (D - 1);     // W1 col (output dim)
    W1T[n * D + k] = f2bf(W1[t]);
  }
  if (t < nS) S[t] = 0.f;
}

// ---------------- main: g = relu(x@W1+b1), segment-sum into S ----------------
// No LDS, no barriers. 256 threads = 4 waves; wave w owns output cols [32w,32w+32).
// Each wave loads its MFMA A-fragments straight from global (rows shared across
// waves hit L1/L2), converts f32->bf16 in-register (v_perm pack), MFMAs, and
// reduces segments in registers (C-layout predication + shfl_xor + atomicAdd).
__global__ __launch_bounds__(256, 3)
void fused_mlp_segsum(const float* __restrict__ x1,
                      const int* __restrict__ slices,
                      const u16* __restrict__ W1T,
                      const float* __restrict__ b1,
                      float* __restrict__ S,
                      int E, int B)
{
  const int tid  = threadIdx.x;
  const int wv   = tid >> 6;
  const int lane = tid & 63;
  const int quad = lane >> 4;
  const int l16  = lane & 15;

  const int chunkStart = blockIdx.x * CHUNK;
  const int chunkEnd   = min(chunkStart + CHUNK, E);
  const int ngroups    = (chunkEnd - chunkStart + 15) >> 4;

  // --- B fragments (W1^T) into registers: ct = 2*wv + c ---
  // lane(quad,l16) holds W1T[ct*16+l16][kk*32+quad*8 .. +7]  (verified R1/R2)
  short8 bf[2][4];
  #pragma unroll
  for (int c = 0; c < 2; ++c)
    #pragma unroll
    for (int kk = 0; kk < 4; ++kk)
      bf[c][kk] = *(const short8*)(W1T + ((2 * wv + c) * 16 + l16) * D + kk * 32 + quad * 8);

  const float bias0 = b1[wv * 32 + l16];
  const float bias1 = b1[wv * 32 + 16 + l16];

  // --- current segment: last s with slices[s] <= chunkStart ---
  int l = 0, r = B + 1;
  while (l < r) { int m = (l + r) >> 1; if (slices[m] <= chunkStart) l = m + 1; else r = m; }
  int cur = l - 1;
  float racc0 = 0.f, racc1 = 0.f;

  // A-fragment loads for 16-row group g: lane reads row chunkStart+g*16+l16,
  // cols quad*8 + kk*32 .. +7  (two float4 per kk)
  auto loadGroup = [&](int g, float4 f0[4], float4 f1[4]) {
    int row = chunkStart + g * 16 + l16;
    const float* rp = x1 + (size_t)min(row, E - 1) * D + quad * 8;
    #pragma unroll
    for (int kk = 0; kk < 4; ++kk) {
      f0[kk] = *(const float4*)(rp + kk * 32);
      f1[kk] = *(const float4*)(rp + kk * 32 + 4);
    }
  };

  auto flushSeg = [&](int s) {
    float t0 = racc0, t1 = racc1;
    t0 += __shfl_xor(t0, 16); t0 += __shfl_xor(t0, 32);
    t1 += __shfl_xor(t1, 16); t1 += __shfl_xor(t1, 32);
    if (quad == 0) {
      atomicAdd(&S[s * D + wv * 32 + l16], t0);
      atomicAdd(&S[s * D + wv * 32 + 16 + l16], t1);
    }
    racc0 = 0.f; racc1 = 0.f;
  };

  // compute + segment-reduce one 16-row group from staged registers
  auto compute = [&](int g, const float4 f0[4], const float4 f1[4]) {
    floatx4 a0 = (floatx4){0.f, 0.f, 0.f, 0.f};
    floatx4 a1 = (floatx4){0.f, 0.f, 0.f, 0.f};
    #pragma unroll
    for (int kk = 0; kk < 4; ++kk) {
      union { short8 s; u32 u[4]; } A;
      A.u[0] = pk2bf(f0[kk].x, f0[kk].y);
      A.u[1] = pk2bf(f0[kk].z, f0[kk].w);
      A.u[2] = pk2bf(f1[kk].x, f1[kk].y);
      A.u[3] = pk2bf(f1[kk].z, f1[kk].w);
      a0 = __builtin_amdgcn_mfma_f32_16x16x32_bf16(A.s, bf[0][kk], a0, 0, 0, 0);
      a1 = __builtin_amdgcn_mfma_f32_16x16x32_bf16(A.s, bf[1][kk], a1, 0, 0, 0);
    }
    // bias + relu; C layout: row = quad*4+i, col = ct*16+l16
    #pragma unroll
    for (int i = 0; i < 4; ++i) {
      a0[i] = fmaxf(a0[i] + bias0, 0.f);
      a1[i] = fmaxf(a1[i] + bias1, 0.f);
    }
    const int base = chunkStart + g * 16;
    const int hi16 = min(base + 16, chunkEnd);
    // segments ending within this group
    while (cur < B) {
      int segEnd = slices[cur + 1];
      if (segEnd > hi16) break;
      int loR = max(slices[cur], base) - base;
      int hiR = segEnd - base;
      if (hiR > loR) {
        #pragma unroll
        for (int i = 0; i < 4; ++i) {
          int rowOff = quad * 4 + i;
          bool in = (rowOff >= loR) && (rowOff < hiR);
          racc0 += in ? a0[i] : 0.f;
          racc1 += in ? a1[i] : 0.f;
        }
      }
      flushSeg(cur);
      ++cur;
    }
    // segment continuing past this group
    if (cur < B) {
      int lo = max(slices[cur], base);
      if (lo < hi16) {
        if (lo == base && hi16 == base + 16) {   // fast path: whole group
          #pragma unroll
          for (int i = 0; i < 4; ++i) { racc0 += a0[i]; racc1 += a1[i]; }
        } else {
          int loR = lo - base, hiR = hi16 - base;
          #pragma unroll
          for (int i = 0; i < 4; ++i) {
            int rowOff = quad * 4 + i;
            bool in = (rowOff >= loR) && (rowOff < hiR);
            racc0 += in ? a0[i] : 0.f;
            racc1 += in ? a1[i] : 0.f;
          }
        }
      }
    }
  };

  // ping-pong register staging: ~1-group load lookahead, no barriers anywhere
  float4 c0[4], c1[4], n0[4], n1[4];
  loadGroup(0, c0, c1);
  for (int g = 0; g < ngroups; g += 2) {
    if (g + 1 < ngroups) loadGroup(g + 1, n0, n1);
    compute(g, c0, c1);
    if (g + 1 < ngroups) {
      if (g + 2 < ngroups) loadGroup(g + 2, c0, c1);
      compute(g + 1, n0, n1);
    }
  }

  // final flush for the segment spilling past chunkEnd
  if (cur < B && slices[cur] < chunkEnd) flushSeg(cur);
}

// ---------------- finish: out = ((S/cnt)@W2+b2)@W3+b3 ; empty -> b3 ----------------
__global__ __launch_bounds__(128)
void finish_mlp(const float* __restrict__ S, const int* __restrict__ slices,
                const float* __restrict__ W2, const float* __restrict__ b2,
                const float* __restrict__ W3, const float* __restrict__ b3,
                float* __restrict__ out, int B)
{
  __shared__ float v0[D];
  __shared__ float v1[D];
  int s = blockIdx.x;
  int j = threadIdx.x;
  int c0 = slices[s], c1 = slices[s + 1];
  int cnt = c1 - c0;
  if (cnt <= 0) { out[s * D + j] = b3[j]; return; }   // uniform branch
  v0[j] = S[s * D + j] * (1.f / (float)cnt);
  __syncthreads();
  float a = b2[j];
  #pragma unroll 8
  for (int k = 0; k < D; ++k) a = fmaf(v0[k], W2[k * D + j], a);
  v1[j] = a;
  __syncthreads();
  float o = b3[j];
  #pragma unroll 8
  for (int k = 0; k < D; ++k) o = fmaf(v1[k], W3[k * D + j], o);
  out[s * D + j] = o;
}

extern "C" void kernel_launch(void* const* d_in, const int* in_sizes, int n_in,
                              void* d_out, int out_size, void* d_ws, size_t ws_size,
                              hipStream_t stream) {
  const float* x1     = (const float*)d_in[0];
  const int*   slices = (const int*)d_in[1];
  const float* W1     = (const float*)d_in[2];
  const float* b1     = (const float*)d_in[3];
  const float* W2     = (const float*)d_in[4];
  const float* b2     = (const float*)d_in[5];
  const float* W3     = (const float*)d_in[6];
  const float* b3     = (const float*)d_in[7];
  float* out = (float*)d_out;

  const int E = in_sizes[0] / D;
  const int B = in_sizes[1] - 1;

  float* S   = (float*)d_ws;                               // B*D f32
  u16*   W1T = (u16*)((char*)d_ws + (size_t)B * D * 4);    // D*D bf16

  int nS = B * D;
  prep_kernel<<<(nS + 255) / 256, 256, 0, stream>>>(W1, W1T, S, nS);

  int nblk = (E + CHUNK - 1) / CHUNK;
  fused_mlp_segsum<<<nblk, 256, 0, stream>>>(x1, slices, W1T, b1, S, E, B);

  finish_mlp<<<B, D, 0, stream>>>(S, slices, W2, b2, W3, b3, out, B);
}